// Round 1
// baseline (753.305 us; speedup 1.0000x reference)
//
#include <hip/hip_runtime.h>
#include <hip/hip_bf16.h>
#include <math.h>

#define IN_CH 256
#define SQ_CH 64
#define NB    32
#define HW    12544           // 112*112
#define HW4   3136            // HW / 4 (float4 count per plane)

// ---------------------------------------------------------------------------
// Kernel 1: global average pool. One block per (n,c) plane.
// ---------------------------------------------------------------------------
__global__ __launch_bounds__(256) void se_pool(const float* __restrict__ x,
                                               float* __restrict__ s) {
    const int plane = blockIdx.x;                 // n*IN_CH + c
    const float4* xp = (const float4*)(x + (size_t)plane * HW);

    float acc = 0.f;
    for (int i = threadIdx.x; i < HW4; i += 256) {
        float4 v = xp[i];
        acc += (v.x + v.y) + (v.z + v.w);
    }
    // wave (64-lane) shuffle reduction
    #pragma unroll
    for (int off = 32; off > 0; off >>= 1)
        acc += __shfl_down(acc, off, 64);

    __shared__ float tmp[4];
    const int lane = threadIdx.x & 63;
    const int wave = threadIdx.x >> 6;
    if (lane == 0) tmp[wave] = acc;
    __syncthreads();
    if (threadIdx.x == 0) {
        float t = (tmp[0] + tmp[1]) + (tmp[2] + tmp[3]);
        s[plane] = t * (1.0f / (float)HW);
    }
}

// ---------------------------------------------------------------------------
// Kernel 2: FC-reduce + ReLU + FC-expand + sigmoid. One block per sample n.
// ---------------------------------------------------------------------------
__global__ __launch_bounds__(256) void se_gate(const float* __restrict__ s,
                                               const float* __restrict__ w_reduce,
                                               const float* __restrict__ b_reduce,
                                               const float* __restrict__ w_expand,
                                               const float* __restrict__ b_expand,
                                               float* __restrict__ gate) {
    const int n = blockIdx.x;
    __shared__ float sv[IN_CH];
    __shared__ float rv[SQ_CH];

    sv[threadIdx.x] = s[n * IN_CH + threadIdx.x];
    __syncthreads();

    if (threadIdx.x < SQ_CH) {
        const float* w = w_reduce + threadIdx.x * IN_CH;   // [SQ_CH, IN_CH]
        float acc = b_reduce[threadIdx.x];
        #pragma unroll 8
        for (int c = 0; c < IN_CH; ++c) acc = fmaf(sv[c], w[c], acc);
        rv[threadIdx.x] = fmaxf(acc, 0.f);
    }
    __syncthreads();

    {
        const float* w = w_expand + threadIdx.x * SQ_CH;   // [IN_CH, SQ_CH]
        float acc = b_expand[threadIdx.x];
        #pragma unroll 8
        for (int k = 0; k < SQ_CH; ++k) acc = fmaf(rv[k], w[k], acc);
        gate[n * IN_CH + threadIdx.x] = 1.0f / (1.0f + expf(-acc));
    }
}

// ---------------------------------------------------------------------------
// Kernel 3: out = gate[n,c] * x. One block per (n,c) plane.
// ---------------------------------------------------------------------------
__global__ __launch_bounds__(256) void se_scale(const float* __restrict__ x,
                                                const float* __restrict__ gate,
                                                float* __restrict__ out) {
    const int plane = blockIdx.x;
    const float g = gate[plane];
    const float4* xp = (const float4*)(x + (size_t)plane * HW);
    float4*       op = (float4*)(out + (size_t)plane * HW);

    for (int i = threadIdx.x; i < HW4; i += 256) {
        float4 v = xp[i];
        v.x *= g; v.y *= g; v.z *= g; v.w *= g;
        op[i] = v;
    }
}

extern "C" void kernel_launch(void* const* d_in, const int* in_sizes, int n_in,
                              void* d_out, int out_size, void* d_ws, size_t ws_size,
                              hipStream_t stream) {
    const float* x        = (const float*)d_in[0];
    const float* w_reduce = (const float*)d_in[1];
    const float* b_reduce = (const float*)d_in[2];
    const float* w_expand = (const float*)d_in[3];
    const float* b_expand = (const float*)d_in[4];
    float* out = (float*)d_out;

    float* s    = (float*)d_ws;                 // [NB, IN_CH]  (32 KB)
    float* gate = s + NB * IN_CH;               // [NB, IN_CH]  (32 KB)

    const int planes = NB * IN_CH;              // 8192

    se_pool <<<planes, 256, 0, stream>>>(x, s);
    se_gate <<<NB, 256, 0, stream>>>(s, w_reduce, b_reduce, w_expand, b_expand, gate);
    se_scale<<<planes, 256, 0, stream>>>(x, gate, out);
}